// Round 1
// baseline (336.349 us; speedup 1.0000x reference)
//
#include <hip/hip_runtime.h>
#include <math.h>

#define D_MODEL 768
#define D_STATE 64
#define BATCH   2
#define SEQ     2048
#define M_TOTAL (BATCH * SEQ)   // 4096

#define BM 64
#define BN 64
#define BK 16

// ---------------- LayerNorm: one wave per row of 768 ----------------
__global__ __launch_bounds__(256) void ln_kernel(const float* __restrict__ x,
                                                 const float* __restrict__ gamma,
                                                 const float* __restrict__ beta,
                                                 float* __restrict__ xn) {
    int row  = blockIdx.x * 4 + (threadIdx.x >> 6);
    int lane = threadIdx.x & 63;
    const float* xr = x + (size_t)row * D_MODEL;
    float4 v[3];
    v[0] = *(const float4*)(xr + lane * 4);
    v[1] = *(const float4*)(xr + 256 + lane * 4);
    v[2] = *(const float4*)(xr + 512 + lane * 4);
    float s = 0.f, ss = 0.f;
#pragma unroll
    for (int i = 0; i < 3; ++i) {
        s  += v[i].x + v[i].y + v[i].z + v[i].w;
        ss += v[i].x * v[i].x + v[i].y * v[i].y + v[i].z * v[i].z + v[i].w * v[i].w;
    }
#pragma unroll
    for (int off = 1; off < 64; off <<= 1) {
        s  += __shfl_xor(s, off, 64);
        ss += __shfl_xor(ss, off, 64);
    }
    float mean = s * (1.0f / 768.0f);
    float var  = ss * (1.0f / 768.0f) - mean * mean;
    float inv  = 1.0f / sqrtf(var + 1e-5f);
    float* xo = xn + (size_t)row * D_MODEL;
#pragma unroll
    for (int i = 0; i < 3; ++i) {
        int c = i * 256 + lane * 4;
        float4 g  = *(const float4*)(gamma + c);
        float4 bb = *(const float4*)(beta + c);
        float4 o;
        o.x = (v[i].x - mean) * inv * g.x + bb.x;
        o.y = (v[i].y - mean) * inv * g.y + bb.y;
        o.z = (v[i].z - mean) * inv * g.z + bb.z;
        o.w = (v[i].w - mean) * inv * g.w + bb.w;
        *(float4*)(xo + c) = o;
    }
}

// ---------------- in_proj GEMM: u = xn @ W_in^T + b_in, written TRANSPOSED as uT[b][d][s] ----------------
__global__ __launch_bounds__(256) void gemm_in(const float* __restrict__ A,   // xn [4096,768]
                                               const float* __restrict__ W,   // W_in [768,768] (row n holds K)
                                               const float* __restrict__ bias,
                                               float* __restrict__ uT) {      // [2][768][2048]
    __shared__ float As[BK][BM + 4];
    __shared__ float Bs[BK][BN + 4];
    int tid = threadIdx.x;
    int bm = blockIdx.x * BM;
    int bn = blockIdx.y * BN;
    int tx = tid & 15, ty = tid >> 4;
    int lrow = tid >> 2;
    int lcol = (tid & 3) << 2;
    float acc[4][4] = {};
    for (int k0 = 0; k0 < D_MODEL; k0 += BK) {
        float4 a4 = *(const float4*)(A + (size_t)(bm + lrow) * D_MODEL + k0 + lcol);
        float4 b4 = *(const float4*)(W + (size_t)(bn + lrow) * D_MODEL + k0 + lcol);
        As[lcol + 0][lrow] = a4.x; As[lcol + 1][lrow] = a4.y;
        As[lcol + 2][lrow] = a4.z; As[lcol + 3][lrow] = a4.w;
        Bs[lcol + 0][lrow] = b4.x; Bs[lcol + 1][lrow] = b4.y;
        Bs[lcol + 2][lrow] = b4.z; Bs[lcol + 3][lrow] = b4.w;
        __syncthreads();
#pragma unroll
        for (int k = 0; k < BK; ++k) {
            float4 av = *(const float4*)&As[k][ty << 2];
            float4 bv = *(const float4*)&Bs[k][tx << 2];
            float a[4] = {av.x, av.y, av.z, av.w};
            float b[4] = {bv.x, bv.y, bv.z, bv.w};
#pragma unroll
            for (int i = 0; i < 4; ++i)
#pragma unroll
                for (int j = 0; j < 4; ++j)
                    acc[i][j] = fmaf(a[i], b[j], acc[i][j]);
        }
        __syncthreads();
    }
    int m0 = bm + (ty << 2);
    int b  = m0 >> 11;       // batch
    int s  = m0 & 2047;      // seq pos
#pragma unroll
    for (int j = 0; j < 4; ++j) {
        int n = bn + (tx << 2) + j;
        float bv = bias[n];
        float4 o = make_float4(acc[0][j] + bv, acc[1][j] + bv, acc[2][j] + bv, acc[3][j] + bv);
        *(float4*)(uT + (size_t)b * D_MODEL * SEQ + (size_t)n * SEQ + s) = o;
    }
}

// ---------------- SSM scan: one wave per (b,d) channel, lane = state index ----------------
__global__ __launch_bounds__(64) void scan_kernel(const float* __restrict__ uT,
                                                  const float* __restrict__ log_A,
                                                  const float* __restrict__ B_p,
                                                  const float* __restrict__ C_p,
                                                  const float* __restrict__ D_p,
                                                  const float* __restrict__ log_dt,
                                                  float* __restrict__ yT) {
    int d = blockIdx.x;      // 0..767
    int b = blockIdx.y;      // 0..1
    int lane = threadIdx.x;  // state n
    float dt = expf(log_dt[d]);
    int idx = d * 64 + lane;
    float Ab = expf(-dt * expf(log_A[idx]));
    float Bb = B_p[idx] * dt;
    float Cc = C_p[idx];
    float Dd = D_p[d];
    const float* up = uT + (size_t)b * D_MODEL * SEQ + (size_t)d * SEQ;
    float*       yp = yT + (size_t)b * D_MODEL * SEQ + (size_t)d * SEQ;
    __shared__ float P[64][68];   // [t mod 64][state], pad 68 keeps float4 align
    float h = 0.f;
    for (int t0 = 0; t0 < SEQ; t0 += 64) {
        float uc = up[t0 + lane];   // coalesced: 64 timesteps per wave
#pragma unroll
        for (int j = 0; j < 64; ++j) {
            float ut = __shfl(uc, j, 64);     // broadcast timestep t0+j (v_readlane, literal)
            h = fmaf(Ab, h, Bb * ut);
            P[j][lane] = h * Cc;
        }
        __syncthreads();
        float ysum = 0.f;
#pragma unroll
        for (int q = 0; q < 16; ++q) {
            float4 pv = *(const float4*)&P[lane][q * 4];
            ysum += (pv.x + pv.y) + (pv.z + pv.w);
        }
        yp[t0 + lane] = fmaf(Dd, uc, ysum);   // coalesced store
        __syncthreads();
    }
}

// ---------------- out_proj GEMM: out = y @ W_out^T + b_out + x  (A read from transposed yT) ----------------
__global__ __launch_bounds__(256) void gemm_out(const float* __restrict__ yT,  // [2][768][2048]
                                                const float* __restrict__ W,   // W_out [768,768]
                                                const float* __restrict__ bias,
                                                const float* __restrict__ resid, // x [4096,768]
                                                float* __restrict__ out) {       // [4096,768]
    __shared__ float As[BK][BM + 4];
    __shared__ float Bs[BK][BN + 4];
    int tid = threadIdx.x;
    int bm = blockIdx.x * BM;
    int bn = blockIdx.y * BN;
    int tx = tid & 15, ty = tid >> 4;
    int lrow = tid >> 2;
    int lcol = (tid & 3) << 2;
    int drow = tid >> 4;            // 0..15 : k-row of A tile
    int scol = (tid & 15) << 2;     // 0..60 : m-col of A tile
    int b  = bm >> 11;
    int s0 = bm & 2047;
    const float* Abase = yT + (size_t)b * D_MODEL * SEQ + s0;
    float acc[4][4] = {};
    for (int k0 = 0; k0 < D_MODEL; k0 += BK) {
        float4 a4 = *(const float4*)(Abase + (size_t)(k0 + drow) * SEQ + scol);
        float4 b4 = *(const float4*)(W + (size_t)(bn + lrow) * D_MODEL + k0 + lcol);
        *(float4*)&As[drow][scol] = a4;   // already [k][m] orientation
        Bs[lcol + 0][lrow] = b4.x; Bs[lcol + 1][lrow] = b4.y;
        Bs[lcol + 2][lrow] = b4.z; Bs[lcol + 3][lrow] = b4.w;
        __syncthreads();
#pragma unroll
        for (int k = 0; k < BK; ++k) {
            float4 av = *(const float4*)&As[k][ty << 2];
            float4 bv = *(const float4*)&Bs[k][tx << 2];
            float a[4] = {av.x, av.y, av.z, av.w};
            float bb[4] = {bv.x, bv.y, bv.z, bv.w};
#pragma unroll
            for (int i = 0; i < 4; ++i)
#pragma unroll
                for (int j = 0; j < 4; ++j)
                    acc[i][j] = fmaf(a[i], bb[j], acc[i][j]);
        }
        __syncthreads();
    }
#pragma unroll
    for (int i = 0; i < 4; ++i) {
        int m  = bm + (ty << 2) + i;
        int n0 = bn + (tx << 2);
        float4 bv = *(const float4*)(bias + n0);
        float4 rv = *(const float4*)(resid + (size_t)m * D_MODEL + n0);
        float4 o = make_float4(acc[i][0] + bv.x + rv.x,
                               acc[i][1] + bv.y + rv.y,
                               acc[i][2] + bv.z + rv.z,
                               acc[i][3] + bv.w + rv.w);
        *(float4*)(out + (size_t)m * D_MODEL + n0) = o;
    }
}

extern "C" void kernel_launch(void* const* d_in, const int* in_sizes, int n_in,
                              void* d_out, int out_size, void* d_ws, size_t ws_size,
                              hipStream_t stream) {
    const float* x        = (const float*)d_in[0];
    const float* ln_gamma = (const float*)d_in[1];
    const float* ln_beta  = (const float*)d_in[2];
    const float* W_in     = (const float*)d_in[3];
    const float* b_in     = (const float*)d_in[4];
    const float* log_A    = (const float*)d_in[5];
    const float* B_p      = (const float*)d_in[6];
    const float* C_p      = (const float*)d_in[7];
    const float* D_p      = (const float*)d_in[8];
    const float* log_dt   = (const float*)d_in[9];
    const float* W_out    = (const float*)d_in[10];
    const float* b_out    = (const float*)d_in[11];
    float* out = (float*)d_out;

    float* xn = (float*)d_ws;                               // [4096,768]
    float* uT = xn + (size_t)M_TOTAL * D_MODEL;             // [2][768][2048]
    float* yT = uT + (size_t)M_TOTAL * D_MODEL;             // [2][768][2048]

    ln_kernel<<<dim3(M_TOTAL / 4), dim3(256), 0, stream>>>(x, ln_gamma, ln_beta, xn);
    gemm_in<<<dim3(M_TOTAL / BM, D_MODEL / BN), dim3(256), 0, stream>>>(xn, W_in, b_in, uT);
    scan_kernel<<<dim3(D_MODEL, BATCH), dim3(64), 0, stream>>>(uT, log_A, B_p, C_p, D_p, log_dt, yT);
    gemm_out<<<dim3(M_TOTAL / BM, D_MODEL / BN), dim3(256), 0, stream>>>(yT, W_out, b_out, x, out);
}